// Round 17
// baseline (49.394 us; speedup 1.0000x reference)
//
#include <hip/hip_runtime.h>

// Delay-logistic DDE, forward Euler, d independent scalar components.
// x_{i+1} = x_i * m_i,  m_i = (1+a) - a*th1*y_i;  y_i = x(i-100) (hist = x_0).
// Output: out[j*(N+1) + t] = x_t  (row-major [d, N+1]).
//
// Round 17: LINE-ALIGNED x4 drain. r12-r16 nulled sync, density, batching,
// and residency; the invariant across the 31-33us plateau is 4B-aligned
// stores partially covering 128B lines (4004B row stride). Here every main
// store is a 16B-aligned dwordx4 covering WHOLE 128B lines:
//   line-aligned cols of row r: c ≡ -9r (mod 32)   [1001 ≡ 9 mod 32]
//   consumer writes per-row aligned 32-col groups (8 lanes x 4 cols each),
//   one <=56-lane x4 store per row per phase; group straddling a phase
//   boundary is served by a 32-col prefix overlap staged by the producer.
//   Partial-line stores remain ONLY at row head (phase 0, <32 cols) and row
//   tail (phase 4, <32 cols + col 1000) = 2 partial lines per ROW vs 2 per
//   400B chunk before (16x fewer).
// Kept: 1P+3C waves, zero recompute, LDS flags + lgkmcnt-only fences (vmcnt
// never drained in-loop), h[100] in VGPRs via macro-LITERAL indices + (256,1).

constexpr int NT   = 1000;          // N steps (setup_inputs: N=1000)
constexpr int NTAU = 100;           // delay = ring size
constexpr int NPH  = 5;             // phases (2 tiles each)
constexpr int PCOL = 200;           // columns per phase
constexpr int NP1  = NT + 1;        // 1001 columns per row
constexpr int COMP = 64;            // components per block (= producer lanes)
constexpr int LSTR = 233;           // 32 prefix + 200 cols + 1 final
constexpr int NCW  = 3;             // consumer waves

// Literal-index repetition macros (SROA-proof: every h index is a literal).
#define R2(F,B)   F(B) F((B)+1)
#define R5(F,B)   F(B) F((B)+1) F((B)+2) F((B)+3) F((B)+4)
#define R25(F,B)  R5(F,B) R5(F,(B)+5) R5(F,(B)+10) R5(F,(B)+15) R5(F,(B)+20)
#define R32(F,B)  R25(F,B) R5(F,(B)+25) R2(F,(B)+30)
#define R50(F,B)  R25(F,B) R25(F,(B)+25)
#define R100(F)   R50(F,0) R50(F,50)

// LDS-only ordering point: pins compiler order and drains the DS pipe.
// NEVER waits on vmcnt -> global stores keep streaming.
#define LDS_ORDER() do {                                    \
    __builtin_amdgcn_sched_barrier(0);                      \
    asm volatile("s_waitcnt lgkmcnt(0)" ::: "memory");      \
    __builtin_amdgcn_sched_barrier(0);                      \
} while (0)

__global__ __launch_bounds__(256, 1)   // min 1 wave/EU: full VGPR budget
void ndde_kernel(const float* __restrict__ x0,
                 const float* __restrict__ tau,
                 const float* __restrict__ params,
                 float* __restrict__ out)
{
    __shared__ float buf[2][COMP][LSTR];   // 119,296 B double-buffered phase image
    __shared__ int   prodf;                // phases published
    __shared__ int   consf[NCW];           // phases consumed, per consumer wave
    const int tid  = threadIdx.x;
    const int wid  = tid >> 6;             // 0 = producer, 1..3 = consumers
    const int lane = tid & 63;
    const int jbase = (int)blockIdx.x * COMP;

    const float dt = 0.01f * tau[0];
    const float a  = dt * params[0];        // dt * theta0
    const float q  = -(a * params[1]);      // -dt*theta0*theta1
    const float p  = 1.0f + a;

    if (tid == 0) { prodf = 0; consf[0] = 0; consf[1] = 0; consf[2] = 0; }
    __syncthreads();                        // flag init only (once; queues empty)

    volatile int* vprod = &prodf;
    volatile int* vcons = consf;

    if (wid == 0) {
        // ---------------- producer ----------------
        float x = x0[jbase + lane];
        float h[NTAU];                      // history ring; lives in VGPRs
#define INIT_H(K) h[(K)] = x;
        R100(INIT_H)
#define STEP(K) { const float y_ = h[(K)]; h[(K)] = x; x *= fmaf(q, y_, p); }
#define PFX(K)  bp[(K)] = h[68+(K)];       // cols 200ph-32..-1 (straddle overlap)
#define STG0(K) bp[32+(K)]  = h[(K)];      // phase cols 0..99
#define STG1(K) bp[132+(K)] = h[(K)];      // phase cols 100..199

#pragma clang loop unroll(disable)          // keep body I-cache-resident
        for (int ph = 0; ph < NPH; ++ph) {
            if (ph >= 2) {                  // buf[ph&1] holds phase ph-2: wait consumed
                while (vcons[0] < ph - 1 || vcons[1] < ph - 1 || vcons[2] < ph - 1)
                    __builtin_amdgcn_s_sleep(1);
                LDS_ORDER();                // poll -> overwrite (cross-wave WAR)
            }
            float* bp = &buf[ph & 1][lane][0];
            if (ph > 0) { R32(PFX, 0) }     // h still holds prev phase's last tile
            R100(STEP)                      // h[k] = x_{200ph+k}
            R100(STG0)
            R100(STEP)                      // h[k] = x_{200ph+100+k}
            R100(STG1)
            if (ph == NPH - 1) bp[232] = x; // col 1000 = x_N into the image
            LDS_ORDER();                    // data writes drain before flag (RAW)
            *vprod = ph + 1;                // publish phase
        }
    } else {
        // ---------------- consumers ----------------
        const int cw = wid - 1;
        const int r0 = (cw == 0) ? 0 : (cw == 1) ? 22 : 43;
        const int rn = (cw == 0) ? 22 : 21;              // 22+21+21 = 64

#pragma clang loop unroll(disable)
        for (int ph = 0; ph < NPH; ++ph) {
            while (*vprod < ph + 1)         // wait for phase
                __builtin_amdgcn_s_sleep(1);
            LDS_ORDER();                    // poll -> data reads (cross-wave RAW)
            const int Lp = PCOL * ph;                    // prev col limit
            const int Lc = (ph == NPH - 1) ? (NT + 1) : (Lp + PCOL);

            for (int rr = 0; rr < rn; ++rr) {
                const int r   = r0 + rr;
                const int off = (32 - ((9 * r) & 31)) & 31;  // first aligned col
                const int cp  = (ph == 0) ? 0 : (Lp - off) >> 5; // groups done
                const int cn  = (Lc - off) >> 5;                 // groups after
                const int s   = off + (cp << 5);                 // aligned start col
                const int nl  = (cn - cp) << 3;                  // lanes (8/group)
                const float* br = &buf[ph & 1][r][0];
                float* rowp = out + (jbase + r) * NP1;

                if (lane < nl) {            // full-line x4 store (16B-aligned)
                    const int col = s + 4 * lane;
                    const int idx = col - Lp + 32;
                    float4 v;
                    v.x = br[idx]; v.y = br[idx + 1];
                    v.z = br[idx + 2]; v.w = br[idx + 3];
                    *(float4*)(rowp + col) = v;
                }
                if (ph == 0 && lane < off)  // row head fragment (cols 0..off-1)
                    rowp[lane] = br[32 + lane];
                if (ph == NPH - 1) {        // row tail fragment (incl. col 1000)
                    const int t0 = off + (cn << 5);
                    if (lane < (NT + 1) - t0)
                        rowp[t0 + lane] = br[t0 + lane - Lp + 32];
                }
            }
            LDS_ORDER();                    // ds_reads drained (stores NOT waited)
            vcons[cw] = ph + 1;             // release buf[ph&1]
        }
    }
}

extern "C" void kernel_launch(void* const* d_in, const int* in_sizes, int n_in,
                              void* d_out, int out_size, void* d_ws, size_t ws_size,
                              hipStream_t stream) {
    const float* x0     = (const float*)d_in[0];
    const float* tau    = (const float*)d_in[1];
    const float* params = (const float*)d_in[2];
    float* out = (float*)d_out;
    const int d = in_sizes[0];              // 32768
    const int nblocks = d / COMP;           // 512 blocks x 256 threads
    ndde_kernel<<<nblocks, 256, 0, stream>>>(x0, tau, params, out);
}

// Round 18
// 47.889 us; speedup vs baseline: 1.0314x; 1.0314x over previous
//
#include <hip/hip_runtime.h>

// Delay-logistic DDE, forward Euler, d independent scalar components.
// x_{i+1} = x_i * m_i,  m_i = (1+a) - a*th1*y_i;  y_i = x(i-100) (hist = x_0).
// Output: out[j*(N+1) + t] = x_t  (row-major [d, N+1]).
//
// Round 18: aligned-x4 drain, implemented WITHOUT r17's latency serialization.
// Theory: L2/HBM write throughput is bounded by per-instruction line coverage
// (fill: 1KB wave-stores, 8 full lines/instr, 6.8TB/s; r12-r16: 256/144B
// wave-stores, 2-3 mostly-partial lines/instr, 4.2TB/s plateau).
// Here: per row per 200-col phase ONE ds_read_b128 + ONE contiguous 800B
// dwordx4 wave-store. 16B alignment is exact: col c of global row j is
// aligned iff c ≡ -j (mod 4); LDS stride 205 (≡1 mod 4, odd->bank-clean) and
// a 4-col staged prefix make LDS and HBM addresses 16B-aligned for ALL rows
// (r*205 + idxbase ≡ 0 mod 4). Phase-straddling groups come from the prefix;
// scalar leftovers only at trajectory head (ph0, <=3 cols) and tail (ph4,
// <=3 cols). x_1000 is staged into the image (no scattered store).
// Kept: r16 skeleton -- 1P+3C waves, zero recompute, LDS flags + lgkmcnt-only
// fences (vmcnt never drained in-loop), h[100] in VGPRs via macro-LITERAL
// indices + (256,1), 2-row read batching (r14).

constexpr int NT   = 1000;          // N steps (setup_inputs: N=1000)
constexpr int NTAU = 100;           // delay = ring size
constexpr int NPH  = 5;             // phases (2 tiles each)
constexpr int PCOL = 200;           // columns per phase
constexpr int NP1  = NT + 1;        // 1001 columns per row
constexpr int COMP = 64;            // components per block (= producer lanes)
constexpr int LSTR = 205;           // 4 prefix + 200 cols + 1 final; ≡1 mod 4, odd
constexpr int NCW  = 3;             // consumer waves

// Literal-index repetition macros (SROA-proof: every h index is a literal).
#define R4(F,B)   F(B) F((B)+1) F((B)+2) F((B)+3)
#define R5(F,B)   F(B) F((B)+1) F((B)+2) F((B)+3) F((B)+4)
#define R25(F,B)  R5(F,B) R5(F,(B)+5) R5(F,(B)+10) R5(F,(B)+15) R5(F,(B)+20)
#define R50(F,B)  R25(F,B) R25(F,(B)+25)
#define R100(F)   R50(F,0) R50(F,50)

// LDS-only ordering point: pins compiler order and drains the DS pipe.
// NEVER waits on vmcnt -> global stores keep streaming.
#define LDS_ORDER() do {                                    \
    __builtin_amdgcn_sched_barrier(0);                      \
    asm volatile("s_waitcnt lgkmcnt(0)" ::: "memory");      \
    __builtin_amdgcn_sched_barrier(0);                      \
} while (0)

__global__ __launch_bounds__(256, 1)   // min 1 wave/EU: full VGPR budget
void ndde_kernel(const float* __restrict__ x0,
                 const float* __restrict__ tau,
                 const float* __restrict__ params,
                 float* __restrict__ out)
{
    __shared__ float buf[2][COMP][LSTR];   // 104,960 B double-buffered phase image
    __shared__ int   prodf;                // phases published
    __shared__ int   consf[NCW];           // phases consumed, per consumer wave
    const int tid  = threadIdx.x;
    const int wid  = tid >> 6;             // 0 = producer, 1..3 = consumers
    const int lane = tid & 63;
    const int jbase = (int)blockIdx.x * COMP;   // multiple of 64 -> ≡0 mod 4

    const float dt = 0.01f * tau[0];
    const float a  = dt * params[0];        // dt * theta0
    const float q  = -(a * params[1]);      // -dt*theta0*theta1
    const float p  = 1.0f + a;

    if (tid == 0) { prodf = 0; consf[0] = 0; consf[1] = 0; consf[2] = 0; }
    __syncthreads();                        // flag init only (once; queues empty)

    volatile int* vprod = &prodf;
    volatile int* vcons = consf;

    if (wid == 0) {
        // ---------------- producer ----------------
        float x = x0[jbase + lane];
        float h[NTAU];                      // history ring; lives in VGPRs
#define INIT_H(K) h[(K)] = x;
        R100(INIT_H)
#define STEP(K) { const float y_ = h[(K)]; h[(K)] = x; x *= fmaf(q, y_, p); }
#define PFX(K)  bp[(K)]     = h[96+(K)];   // cols 200ph-4..-1 (straddle prefix)
#define STG0(K) bp[4+(K)]   = h[(K)];      // phase cols 0..99   (idx = col+4)
#define STG1(K) bp[104+(K)] = h[(K)];      // phase cols 100..199

#pragma clang loop unroll(disable)          // keep body I-cache-resident
        for (int ph = 0; ph < NPH; ++ph) {
            if (ph >= 2) {                  // buf[ph&1] holds phase ph-2: wait consumed
                while (vcons[0] < ph - 1 || vcons[1] < ph - 1 || vcons[2] < ph - 1)
                    __builtin_amdgcn_s_sleep(1);
                LDS_ORDER();                // poll -> overwrite (cross-wave WAR)
            }
            float* bp = &buf[ph & 1][lane][0];
            if (ph > 0) { R4(PFX, 0) }      // h still holds prev tile's cols
            R100(STEP)                      // h[k] = x_{200ph+k}
            R100(STG0)
            R100(STEP)                      // h[k] = x_{200ph+100+k}
            R100(STG1)
            if (ph == NPH - 1) bp[204] = x; // col 1000 = x_N into the image
            LDS_ORDER();                    // data writes drain before flag (RAW)
            *vprod = ph + 1;                // publish phase
        }
    } else {
        // ---------------- consumers ----------------
        const int cw = wid - 1;
        const int r0 = (cw == 0) ? 0 : (cw == 1) ? 22 : 43;
        const int rn = (cw == 0) ? 22 : 21;              // 22+21+21 = 64

#pragma clang loop unroll(disable)
        for (int ph = 0; ph < NPH; ++ph) {
            while (*vprod < ph + 1)         // wait for phase
                __builtin_amdgcn_s_sleep(1);
            LDS_ORDER();                    // poll -> data reads (cross-wave RAW)
            const float* bb = &buf[ph & 1][0][0];

            // Per row: aligned col groups start at S ≡ o_r (mod 4), o_r=(-r)&3.
            //   ph=0:  S0 = o_r,              G = (o_r==0) ? 50 : 49
            //   ph>=1: S0 = 200ph+((o_r-1)&3)-3, G = 50  (ph=4: o_r==1 -> 51)
            // LDS idx of col c: c - 200ph + 4; both LDS & global 16B-aligned.
            for (int rr = 0; rr < rn; rr += 2) {
                const int  r1 = r0 + rr;
                const bool two = (rr + 1 < rn);
                const int  r2 = two ? (r1 + 1) : r1;

                const int o1 = (-r1) & 3,  o2 = (-r2) & 3;
                const int S1 = (ph == 0) ? o1 : (PCOL * ph + ((o1 - 1) & 3) - 3);
                const int S2 = (ph == 0) ? o2 : (PCOL * ph + ((o2 - 1) & 3) - 3);
                const int G1 = (ph == 0) ? ((o1 == 0) ? 50 : 49)
                             : (ph == NPH - 1 && o1 == 1) ? 51 : 50;
                const int G2 = (ph == 0) ? ((o2 == 0) ? 50 : 49)
                             : (ph == NPH - 1 && o2 == 1) ? 51 : 50;

                const float4* lp1 = (const float4*)(bb + r1 * LSTR + (S1 - PCOL * ph + 4));
                const float4* lp2 = (const float4*)(bb + r2 * LSTR + (S2 - PCOL * ph + 4));
                float* gp1 = out + (size_t)(jbase + r1) * NP1 + S1;
                float* gp2 = out + (size_t)(jbase + r2) * NP1 + S2;

                float4 v1, v2;
                if (lane < G1) v1 = lp1[lane];              // batched b128 reads
                if (two && lane < G2) v2 = lp2[lane];
                if (lane < G1) *(float4*)(gp1 + 4 * lane) = v1;   // 800B contiguous
                if (two && lane < G2) *(float4*)(gp2 + 4 * lane) = v2;

                if (ph == 0) {              // head cols 0..o_r-1 (idx col+4)
                    if (lane < o1) gp1[lane - S1] = bb[r1 * LSTR + 4 + lane];
                    if (two && lane < o2) gp2[lane - S2] = bb[r2 * LSTR + 4 + lane];
                } else if (ph == NPH - 1) { // tail cols 1001-tcnt..1000
                    const int t1 = (o1 == 0) ? 1 : (o1 == 1) ? 0 : (o1 == 2) ? 3 : 2;
                    const int t2 = (o2 == 0) ? 1 : (o2 == 1) ? 0 : (o2 == 2) ? 3 : 2;
                    const int c1 = NP1 - t1, c2 = NP1 - t2;   // first tail col
                    if (lane < t1)
                        out[(size_t)(jbase + r1) * NP1 + c1 + lane] =
                            bb[r1 * LSTR + (c1 - 800 + 4) + lane];
                    if (two && lane < t2)
                        out[(size_t)(jbase + r2) * NP1 + c2 + lane] =
                            bb[r2 * LSTR + (c2 - 800 + 4) + lane];
                }
            }
            LDS_ORDER();                    // ds_reads drained (stores NOT waited)
            vcons[cw] = ph + 1;             // release buf[ph&1]
        }
    }
}

extern "C" void kernel_launch(void* const* d_in, const int* in_sizes, int n_in,
                              void* d_out, int out_size, void* d_ws, size_t ws_size,
                              hipStream_t stream) {
    const float* x0     = (const float*)d_in[0];
    const float* tau    = (const float*)d_in[1];
    const float* params = (const float*)d_in[2];
    float* out = (float*)d_out;
    const int d = in_sizes[0];              // 32768
    const int nblocks = d / COMP;           // 512 blocks x 256 threads
    ndde_kernel<<<nblocks, 256, 0, stream>>>(x0, tau, params, out);
}